// Round 2
// baseline (104.656 us; speedup 1.0000x reference)
//
#include <hip/hip_runtime.h>

#define HW_ (1024 * 1024)

typedef _Float16 half8 __attribute__((ext_vector_type(8)));
typedef __fp16 fp16x2 __attribute__((ext_vector_type(2)));
typedef float f32x16 __attribute__((ext_vector_type(16)));
typedef unsigned int uint;

// ---------------------------------------------------------------------------
// R13 = single-kernel (no build_filter_table dispatch) with the 4KB fp16
// filter table built in LDS per block, branch-free.
// R12 post-mortem: fused per-lane fragment rebuild was wave-DIVERGENT on h
// (both halves of the wave executed both 4-fragment build paths) with ~32
// uncoalesced scalar loads -> +2us on main. R13 replaces it with R11's
// proven table layout, built cooperatively pre-barrier (hidden under image
// staging) and read as 4x ds_read_b128 per lane post-barrier.
// Bank-conflict note: linear table layout would give 16-way conflicts on
// the fragment reads (lane read stride 64B -> banks {0-3,16-19} only), so
// fragments are stored padded: fragment f at byte (f>>2)*80 + (f&3)*16.
// Lane bank starts become (20n)%32 -> 8 distinct -> ~4-way (mild, m136).
// ---------------------------------------------------------------------------

// tap offset dy*5+dx into a 5x5 filter, or -1 for structural zero.
// TAPS[po][kk]; equals R11 tap_from_kk (harness-verified via R12 absmax).
__device__ constexpr short TAPS[2][32] = {
    { 0, 1, 2, 3, 5, 6, 7, 8, 10, 11, 12, 13, 15, 16, 17, 18,
      20, 21, 4, 9, 14, -1, -1, -1, 22, 23, 19, 24, -1, -1, -1, -1 },
    { 1, 2, 3, 4, 6, 7, 8, 9, 11, 12, 13, 14, 16, 17, 18, 19,
      21, 22, 0, 5, 10, -1, -1, -1, 23, 24, 15, 20, -1, -1, -1, -1 },
};

__global__ __launch_bounds__(256, 2)
void demosaick_fused(const float* __restrict__ mosaick,
                     const float* __restrict__ sel_filts,
                     const float* __restrict__ green_filts,
                     float* __restrict__ out) {
    // [0,1360): image tile 20 rows x 68 cols fp16; [1360,1392): zero pad;
    // [1392,3952): padded filter table (256 fragments, 80B per 4-frag group).
    __shared__ __align__(16) _Float16 smem[1392 + 2560];

    const int tid = threadIdx.x;
    const int b   = blockIdx.z;
    const int by0 = blockIdx.y * 16, bx0 = blockIdx.x * 64;
    const float* img = mosaick + (size_t)b * HW_;

    const bool interior = (blockIdx.x != 0) & (blockIdx.x != gridDim.x - 1) &
                          (blockIdx.y != 0) & (blockIdx.y != gridDim.y - 1);
    if (interior) {
        // 680 dwords; dword index == idx; rows of 34 float2.
        uint* smw_w = (uint*)smem;
        for (int idx = tid; idx < 680; idx += 256) {
            int row = idx / 34, c2 = idx - row * 34;
            float2 v = *(const float2*)(img + (size_t)(by0 - 2 + row) * 1024
                                            + (bx0 - 2 + 2 * c2));
            union { fp16x2 h; uint u; } cv;
            cv.h = __builtin_amdgcn_cvt_pkrtz(v.x, v.y);
            smw_w[idx] = cv.u;
        }
    } else {
        for (int idx = tid; idx < 1360; idx += 256) {
            int row = idx / 68, col = idx - row * 68;
            int gy = by0 - 2 + row; gy = gy < 0 ? 0 : (gy > 1023 ? 1023 : gy);
            int gx = bx0 - 2 + col; gx = gx < 0 ? 0 : (gx > 1023 ? 1023 : gx);
            smem[idx] = (_Float16)img[gy * 1024 + gx];
        }
    }
    if (tid < 32) smem[1360 + tid] = (_Float16)0.f;

    // ---- LDS filter-table build (pre-barrier; hides under staging) ----
    // Logical table: half idx e = po*1024 + m*32 + kk (R11 layout).
    // Each thread writes 4 dwords (entry pairs). Branch-free predication.
    {
        uint* tblw = (uint*)(smem + 1392);
        #pragma unroll
        for (int i = 0; i < 4; ++i) {
            const int d   = tid + 256 * i;          // dword entry, e = 2d
            const int po  = d >> 9;
            const int m   = (d >> 4) & 31;
            const int kk0 = (d & 15) * 2;
            const int t   = m & 3;
            const float* fb = (t & 1) ? green_filts : sel_filts;
            const int off = (2 * (m >> 3) + ((m >> 1) & 1)) * 25;
            const int to0 = TAPS[po][kk0], to1 = TAPS[po][kk0 + 1];
            float v0 = (to0 >= 0) ? fb[off + to0] : 0.f;
            float v1 = (to1 >= 0) ? fb[off + to1] : 0.f;
            union { fp16x2 h; uint u; } cv;
            cv.h = __builtin_amdgcn_cvt_pkrtz(v0, v1);
            const int f = d >> 2, wd = d & 3;       // fragment, dword-in-frag
            tblw[(f >> 2) * 20 + (f & 3) * 4 + wd] = cv.u;
        }
    }
    __syncthreads();

    const int lane = tid & 63, w = tid >> 6;
    const int n = lane & 31, h = lane >> 5;       // n: A-row / pixel col

    // A fragments from the padded LDS table (ds_read_b128, ~4-way banks).
    // Fragment f: a0p0=4n+h, a1p0=4n+2+h, p1 adds 128 (-> group +32).
    const char* tb = (const char*)smem + 2784;    // table byte base
    const char* bn = tb + n * 80;                 // group g=n
    const half8 a0p0 = *(const half8*)(bn + h * 16);
    const half8 a1p0 = *(const half8*)(bn + 32 + h * 16);
    const half8 a0p1 = *(const half8*)(bn + 2560 + h * 16);        // g=32+n
    const half8 a1p1 = *(const half8*)(bn + 2560 + 32 + h * 16);

    const uint* smw = (const uint*)smem;
    const unsigned short* sms = (const unsigned short*)smem;
    float* outp = out + (size_t)b * HW_;
    const float L2E = 1.44269504f;

    // ---- Stage 1: ALL B-fragment gathers (independent, overlap latency) ----
    uint B0[4][4], B1[4][4];
    #pragma unroll
    for (int u = 0; u < 4; ++u) {
        const int r  = 4 * w + u;                 // tile row of computed px
        const int po = (u & 1) ^ 1;               // y=by0+r even -> po=1
        const int pb = po, sdx = po ? 0 : 4;
        const int e0 = (r + 2 * h) * 68 + 2 * n + po;
        const int e4 = (r + 4) * 68 + 2 * n + po;
        const int rs0 = h ? 3 : 0, rs1 = h ? 4 : 1;

        B0[u][0] = smw[(e0 + pb) >> 1];
        B0[u][1] = smw[(e0 + pb + 2) >> 1];
        B0[u][2] = smw[(e0 + 68 + pb) >> 1];
        B0[u][3] = smw[(e0 + 68 + pb + 2) >> 1];
        B1[u][0] = smw[(e4 + pb + 2 * h) >> 1];
        uint us0 = sms[(r + rs0) * 68 + 2 * n + po + sdx];
        uint us1 = sms[(r + rs1) * 68 + 2 * n + po + sdx];
        B1[u][1] = us0 | (us1 << 16);
        B1[u][2] = sms[h ? 1360 : ((r + 2) * 68 + 2 * n + po + sdx)];
        B1[u][3] = 0;
    }

    // ---- Stage 2: MFMA + softmax epilogue per group ----
    #pragma unroll
    for (int u = 0; u < 4; ++u) {
        const int r  = 4 * w + u;
        const int po = (u & 1) ^ 1;

        union { uint u4[4]; half8 v; } b0c = {{B0[u][0], B0[u][1], B0[u][2], B0[u][3]}};
        union { uint u4[4]; half8 v; } b1c = {{B1[u][0], B1[u][1], B1[u][2], B1[u][3]}};

        f32x16 acc = {};
        acc = __builtin_amdgcn_mfma_f32_32x32x16_f16(po ? a0p1 : a0p0, b0c.v, acc, 0, 0, 0);
        acc = __builtin_amdgcn_mfma_f32_32x32x16_f16(po ? a1p1 : a1p0, b1c.v, acc, 0, 0, 0);

        // Channel-duplicated A: even regs = sel, odd regs = green (all 8 pairs).
        float se = 0.f, eg = 0.f;
        #pragma unroll
        for (int rr = 0; rr < 16; rr += 2) {
            float e = __builtin_amdgcn_exp2f(acc[rr] * L2E);
            se += e;
            eg = fmaf(e, acc[rr + 1], eg);
        }
        float gh = eg * __builtin_amdgcn_rcpf(se);

        if (h == 1) {
            // pass-through tap lives in this lane's B0 fragment (row r+2):
            // po=1 -> b0[0] (col 2n+2); po=0 -> b0[3] (col 2n+3)
            float pass = (float)(po ? b0c.v[0] : b0c.v[3]);
            float2 o;
            if (po) { o.x = pass; o.y = gh; }     // y even: (pass, comp)
            else    { o.x = gh;   o.y = pass; }   // y odd:  (comp, pass)
            *(float2*)(outp + (size_t)(by0 + r) * 1024 + bx0 + 2 * n) = o;
        }
    }
}

extern "C" void kernel_launch(void* const* d_in, const int* in_sizes, int n_in,
                              void* d_out, int out_size, void* d_ws, size_t ws_size,
                              hipStream_t stream) {
    const float* mosaick     = (const float*)d_in[0];
    const float* sel_filts   = (const float*)d_in[1];
    const float* green_filts = (const float*)d_in[2];
    float* out = (float*)d_out;
    const int B = in_sizes[0] / HW_;          // 8
    dim3 grid(1024 / 64, 1024 / 16, B);       // (16, 64, 8) = 8192 blocks
    dim3 block(256, 1, 1);
    hipLaunchKernelGGL(demosaick_fused, grid, block, 0, stream,
                       mosaick, sel_filts, green_filts, out);
}

// Round 3
// 102.353 us; speedup vs baseline: 1.0225x; 1.0225x over previous
//
#include <hip/hip_runtime.h>

#define HW_ (1024 * 1024)

typedef _Float16 half8 __attribute__((ext_vector_type(8)));
typedef __fp16 fp16x2 __attribute__((ext_vector_type(2)));
typedef float f32x16 __attribute__((ext_vector_type(16)));
typedef unsigned int uint;

// ---------------------------------------------------------------------------
// R14 = revert to R11 (verified best, 101.4us). R12 (103.6) and R13 (104.7)
// both fused the filter-table build into the main kernel and both regressed:
// re-deriving the 4KB table per-block (8192x) costs more than the amortized
// 8-block build kernel + graph node (~1-2us total). The main kernel sits at
// its 67MB HBM floor (~10.6us @ 6.3TB/s achievable); the remaining ~90us of
// dur_us is harness poison fills (2x256MiB @ ~78% HBM peak) — fixed cost.
//
// R11 structure: 2x mfma_32x32x16_f16 per 32-px row-group, precomputed
// filter table in d_ws (L1-resident 16B loads), channel-duplicated A ->
// shuffle-free softmax, all B-fragment LDS gathers hoisted ahead of MFMAs,
// interior-block staging via float2 + cvt_pkrtz -> dword LDS stores.
// ---------------------------------------------------------------------------

__device__ __forceinline__ void tap_from_kk(int po, int kk, int& dy, int& dx) {
    const int pb = po, sdx = po ? 0 : 4;
    dy = -1; dx = 0;
    if (kk < 16)           { int h = kk >> 3, j = kk & 7;
                             dy = 2 * h + (j >> 2); dx = pb + (j & 3); }
    else if (kk < 18)      { dy = 4; dx = pb + (kk - 16); }
    else if (kk == 18)     { dy = 0; dx = sdx; }
    else if (kk == 19)     { dy = 1; dx = sdx; }
    else if (kk == 20)     { dy = 2; dx = sdx; }
    else if (kk >= 24 && kk < 26) { dy = 4; dx = pb + 2 + (kk - 24); }
    else if (kk == 26)     { dy = 3; dx = sdx; }
    else if (kk == 27)     { dy = 4; dx = sdx; }
}

__global__ void build_filter_table(const float* __restrict__ sel_filts,
                                   const float* __restrict__ green_filts,
                                   _Float16* __restrict__ tbl) {
    int idx = blockIdx.x * 256 + threadIdx.x;     // 0..2047
    int po = idx >> 10, m = (idx >> 5) & 31, kk = idx & 31;
    int dy, dx;
    tap_from_kk(po, kk, dy, dx);
    float v = 0.f;
    if (dy >= 0) {
        int t = m & 3;
        int p = 2 * ((m >> 2) >> 1) + (t >> 1);   // pair 0..7 (dup over m>>3)
        v = ((t & 1) ? green_filts : sel_filts)[p * 25 + dy * 5 + dx];
    }
    tbl[idx] = (_Float16)v;
}

__global__ __launch_bounds__(256, 2)
void demosaick_main(const float* __restrict__ mosaick,
                    const _Float16* __restrict__ tbl,
                    float* __restrict__ out) {
    // [0,1360): image tile 20 rows x 68 cols fp16; [1360,1392): zero pad
    __shared__ __align__(16) _Float16 smem[1392];

    const int tid = threadIdx.x;
    const int b   = blockIdx.z;
    const int by0 = blockIdx.y * 16, bx0 = blockIdx.x * 64;
    const float* img = mosaick + (size_t)b * HW_;

    const bool interior = (blockIdx.x != 0) & (blockIdx.x != gridDim.x - 1) &
                          (blockIdx.y != 0) & (blockIdx.y != gridDim.y - 1);
    if (interior) {
        // 680 dwords; dword index == idx; rows of 34 float2.
        uint* smw_w = (uint*)smem;
        for (int idx = tid; idx < 680; idx += 256) {
            int row = idx / 34, c2 = idx - row * 34;
            float2 v = *(const float2*)(img + (size_t)(by0 - 2 + row) * 1024
                                            + (bx0 - 2 + 2 * c2));
            union { fp16x2 h; uint u; } cv;
            cv.h = __builtin_amdgcn_cvt_pkrtz(v.x, v.y);
            smw_w[idx] = cv.u;
        }
    } else {
        for (int idx = tid; idx < 1360; idx += 256) {
            int row = idx / 68, col = idx - row * 68;
            int gy = by0 - 2 + row; gy = gy < 0 ? 0 : (gy > 1023 ? 1023 : gy);
            int gx = bx0 - 2 + col; gx = gx < 0 ? 0 : (gx > 1023 ? 1023 : gx);
            smem[idx] = (_Float16)img[gy * 1024 + gx];
        }
    }
    if (tid < 32) smem[1360 + tid] = (_Float16)0.f;
    __syncthreads();

    const int lane = tid & 63, w = tid >> 6;
    const int n = lane & 31, h = lane >> 5;       // n: A-row / pixel col

    // A fragments from the global table (L1-resident, 16B loads).
    const half8* t8 = (const half8*)tbl;
    const half8 a0p0 = t8[      n * 4 + h];       // po=0, kk=h*8
    const half8 a1p0 = t8[      n * 4 + 2 + h];   // po=0, kk=16+h*8
    const half8 a0p1 = t8[128 + n * 4 + h];       // po=1
    const half8 a1p1 = t8[128 + n * 4 + 2 + h];

    const uint* smw = (const uint*)smem;
    const unsigned short* sms = (const unsigned short*)smem;
    float* outp = out + (size_t)b * HW_;
    const float L2E = 1.44269504f;

    // ---- Stage 1: ALL B-fragment gathers (independent, overlap latency) ----
    uint B0[4][4], B1[4][4];
    #pragma unroll
    for (int u = 0; u < 4; ++u) {
        const int r  = 4 * w + u;                 // tile row of computed px
        const int po = (u & 1) ^ 1;               // y=by0+r even -> po=1
        const int pb = po, sdx = po ? 0 : 4;
        const int e0 = (r + 2 * h) * 68 + 2 * n + po;
        const int e4 = (r + 4) * 68 + 2 * n + po;
        const int rs0 = h ? 3 : 0, rs1 = h ? 4 : 1;

        B0[u][0] = smw[(e0 + pb) >> 1];
        B0[u][1] = smw[(e0 + pb + 2) >> 1];
        B0[u][2] = smw[(e0 + 68 + pb) >> 1];
        B0[u][3] = smw[(e0 + 68 + pb + 2) >> 1];
        B1[u][0] = smw[(e4 + pb + 2 * h) >> 1];
        uint us0 = sms[(r + rs0) * 68 + 2 * n + po + sdx];
        uint us1 = sms[(r + rs1) * 68 + 2 * n + po + sdx];
        B1[u][1] = us0 | (us1 << 16);
        B1[u][2] = sms[h ? 1360 : ((r + 2) * 68 + 2 * n + po + sdx)];
        B1[u][3] = 0;
    }

    // ---- Stage 2: MFMA + softmax epilogue per group ----
    #pragma unroll
    for (int u = 0; u < 4; ++u) {
        const int r  = 4 * w + u;
        const int po = (u & 1) ^ 1;

        union { uint u4[4]; half8 v; } b0c = {{B0[u][0], B0[u][1], B0[u][2], B0[u][3]}};
        union { uint u4[4]; half8 v; } b1c = {{B1[u][0], B1[u][1], B1[u][2], B1[u][3]}};

        f32x16 acc = {};
        acc = __builtin_amdgcn_mfma_f32_32x32x16_f16(po ? a0p1 : a0p0, b0c.v, acc, 0, 0, 0);
        acc = __builtin_amdgcn_mfma_f32_32x32x16_f16(po ? a1p1 : a1p0, b1c.v, acc, 0, 0, 0);

        // Channel-duplicated A: even regs = sel, odd regs = green (all 8 pairs).
        float se = 0.f, eg = 0.f;
        #pragma unroll
        for (int rr = 0; rr < 16; rr += 2) {
            float e = __builtin_amdgcn_exp2f(acc[rr] * L2E);
            se += e;
            eg = fmaf(e, acc[rr + 1], eg);
        }
        float gh = eg * __builtin_amdgcn_rcpf(se);

        if (h == 1) {
            // pass-through tap lives in this lane's B0 fragment (row r+2):
            // po=1 -> b0[0] (col 2n+2); po=0 -> b0[3] (col 2n+3)
            float pass = (float)(po ? b0c.v[0] : b0c.v[3]);
            float2 o;
            if (po) { o.x = pass; o.y = gh; }     // y even: (pass, comp)
            else    { o.x = gh;   o.y = pass; }   // y odd:  (comp, pass)
            *(float2*)(outp + (size_t)(by0 + r) * 1024 + bx0 + 2 * n) = o;
        }
    }
}

// ---- fallback (ws too small): self-contained, verified R9-class kernel ----
__global__ __launch_bounds__(256, 2)
void demosaick_fallback(const float* __restrict__ mosaick,
                        const float* __restrict__ sel_filts,
                        const float* __restrict__ green_filts,
                        float* __restrict__ out) {
    __shared__ __align__(16) _Float16 smem[3456];
    const int tid = threadIdx.x;
    const int b   = blockIdx.z;
    const int by0 = blockIdx.y * 16, bx0 = blockIdx.x * 64;
    const float* img = mosaick + (size_t)b * HW_;

    for (int idx = tid; idx < 1360; idx += 256) {
        int row = idx / 68, col = idx - row * 68;
        int gy = by0 - 2 + row; gy = gy < 0 ? 0 : (gy > 1023 ? 1023 : gy);
        int gx = bx0 - 2 + col; gx = gx < 0 ? 0 : (gx > 1023 ? 1023 : gx);
        smem[idx] = (_Float16)img[gy * 1024 + gx];
    }
    for (int idx = tid; idx < 2048; idx += 256) {
        int po = idx >> 10, m = (idx >> 5) & 31, kk = idx & 31;
        int dy, dx;
        tap_from_kk(po, kk, dy, dx);
        float v = 0.f;
        if (dy >= 0) {
            int t = m & 3;
            int p = 2 * ((m >> 2) >> 1) + (t >> 1);
            v = ((t & 1) ? green_filts : sel_filts)[p * 25 + dy * 5 + dx];
        }
        smem[1360 + idx] = (_Float16)v;
    }
    for (int idx = tid; idx < 32; idx += 256) smem[3408 + idx] = (_Float16)0.f;
    __syncthreads();

    const int lane = tid & 63, w = tid >> 6;
    const int n = lane & 31, h = lane >> 5;
    const half8 a0p0 = *(const half8*)&smem[1360 +        n * 32 + h * 8];
    const half8 a1p0 = *(const half8*)&smem[1360 +        n * 32 + 16 + h * 8];
    const half8 a0p1 = *(const half8*)&smem[1360 + 1024 + n * 32 + h * 8];
    const half8 a1p1 = *(const half8*)&smem[1360 + 1024 + n * 32 + 16 + h * 8];

    const uint* smw = (const uint*)smem;
    const unsigned short* sms = (const unsigned short*)smem;
    float* outp = out + (size_t)b * HW_;
    const float L2E = 1.44269504f;

    #pragma unroll
    for (int u = 0; u < 4; ++u) {
        const int r  = 4 * w + u;
        const int po = (u & 1) ^ 1;
        const int pb = po, sdx = po ? 0 : 4;
        const int e0 = (r + 2 * h) * 68 + 2 * n + po;
        const int e4 = (r + 4) * 68 + 2 * n + po;
        const int rs0 = h ? 3 : 0, rs1 = h ? 4 : 1;

        uint B0x = smw[(e0 + pb) >> 1];
        uint B0y = smw[(e0 + pb + 2) >> 1];
        uint B0z = smw[(e0 + 68 + pb) >> 1];
        uint B0w = smw[(e0 + 68 + pb + 2) >> 1];
        uint B1x = smw[(e4 + pb + 2 * h) >> 1];
        uint us0 = sms[(r + rs0) * 68 + 2 * n + po + sdx];
        uint us1 = sms[(r + rs1) * 68 + 2 * n + po + sdx];
        uint B1y = us0 | (us1 << 16);
        uint B1z = sms[h ? 3408 : ((r + 2) * 68 + 2 * n + po + sdx)];
        uint B1w = 0;

        union { uint u4[4]; half8 v; } b0c = {{B0x, B0y, B0z, B0w}};
        union { uint u4[4]; half8 v; } b1c = {{B1x, B1y, B1z, B1w}};

        f32x16 acc = {};
        acc = __builtin_amdgcn_mfma_f32_32x32x16_f16(po ? a0p1 : a0p0, b0c.v, acc, 0, 0, 0);
        acc = __builtin_amdgcn_mfma_f32_32x32x16_f16(po ? a1p1 : a1p0, b1c.v, acc, 0, 0, 0);

        float se = 0.f, eg = 0.f;
        #pragma unroll
        for (int rr = 0; rr < 16; rr += 2) {
            float e = __builtin_amdgcn_exp2f(acc[rr] * L2E);
            se += e;
            eg = fmaf(e, acc[rr + 1], eg);
        }
        float gh = eg * __builtin_amdgcn_rcpf(se);

        if (h == 1) {
            float pass = (float)(po ? b0c.v[0] : b0c.v[3]);
            float2 o;
            if (po) { o.x = pass; o.y = gh; }
            else    { o.x = gh;   o.y = pass; }
            *(float2*)(outp + (size_t)(by0 + r) * 1024 + bx0 + 2 * n) = o;
        }
    }
}

extern "C" void kernel_launch(void* const* d_in, const int* in_sizes, int n_in,
                              void* d_out, int out_size, void* d_ws, size_t ws_size,
                              hipStream_t stream) {
    const float* mosaick     = (const float*)d_in[0];
    const float* sel_filts   = (const float*)d_in[1];
    const float* green_filts = (const float*)d_in[2];
    float* out = (float*)d_out;
    const int B = in_sizes[0] / HW_;          // 8
    dim3 grid(1024 / 64, 1024 / 16, B);       // (16, 64, 8) = 8192 blocks
    dim3 block(256, 1, 1);

    if (ws_size >= 4096) {
        _Float16* tbl = (_Float16*)d_ws;
        hipLaunchKernelGGL(build_filter_table, dim3(8), dim3(256), 0, stream,
                           sel_filts, green_filts, tbl);
        hipLaunchKernelGGL(demosaick_main, grid, block, 0, stream,
                           mosaick, tbl, out);
    } else {
        hipLaunchKernelGGL(demosaick_fallback, grid, block, 0, stream,
                           mosaick, sel_filts, green_filts, out);
    }
}